// Round 1
// 1015.133 us; speedup vs baseline: 1.0907x; 1.0907x over previous
//
#include <hip/hip_runtime.h>

#define N 8192
#define NITER 20
#define TOLF 1e-10f

typedef float floatx4 __attribute__((ext_vector_type(4)));
typedef unsigned int uintx4 __attribute__((ext_vector_type(4)));

__device__ __forceinline__ unsigned short f2bf_rne(float f) {
  unsigned int u = __float_as_uint(f);
  unsigned int r = u + 0x7fffu + ((u >> 16) & 1u);
  return (unsigned short)(r >> 16);
}
__device__ __forceinline__ unsigned int pk_bf2(float lo, float hi) {
  return (unsigned int)f2bf_rne(lo) | ((unsigned int)f2bf_rne(hi) << 16);
}
__device__ __forceinline__ float bflo(unsigned int u) { return __uint_as_float(u << 16); }
__device__ __forceinline__ float bfhi(unsigned int u) { return __uint_as_float(u & 0xffff0000u); }

// ---------------- init: x=0, r=p=RHS, rt0 = sum(RHS^2) ----------------
__global__ __launch_bounds__(256) void init_kernel(
    const float* __restrict__ RHS, float* __restrict__ x, float* __restrict__ r,
    float* __restrict__ p, float* __restrict__ rt0) {
  int i = blockIdx.x * 256 + threadIdx.x;
  float v = RHS[i];
  x[i] = 0.0f;
  r[i] = v;
  p[i] = v;
  float val = v * v;
  for (int off = 32; off > 0; off >>= 1) val += __shfl_down(val, off, 64);
  __shared__ float bs[4];
  int wave = threadIdx.x >> 6, lane = threadIdx.x & 63;
  if (lane == 0) bs[wave] = val;
  __syncthreads();
  if (threadIdx.x == 0) atomicAdd(rt0, bs[0] + bs[1] + bs[2] + bs[3]);
}

// ---- shared tail: wave reduce, Ap/pAp publish, last block does the update ----
// Deadlock-free: no spinning. All of a block's p/Ap-phase reads precede its
// counter increment (program order + __syncthreads); the last block's vector
// writes follow the acquiring final increment (device-scope acq_rel), same
// idiom the previous verified kernel used for its p update.
__device__ __forceinline__ void finish_iteration(
    float* __restrict__ p, float* __restrict__ x, float* __restrict__ r,
    float* __restrict__ Ap, const float* __restrict__ rt,
    float* __restrict__ pap, float* __restrict__ rt_next,
    int* __restrict__ counter, float acc0, float acc1, int row0) {
  int wave = threadIdx.x >> 6, lane = threadIdx.x & 63;
  for (int off = 32; off > 0; off >>= 1) {
    acc0 += __shfl_down(acc0, off, 64);
    acc1 += __shfl_down(acc1, off, 64);
  }
  __shared__ float bs[16];
  __shared__ int tick;
  if (lane == 0) {
    Ap[row0]     = acc0;
    Ap[row0 + 1] = acc1;
    bs[wave] = p[row0] * acc0 + p[row0 + 1] * acc1;
  }
  __syncthreads();
  if (threadIdx.x == 0) {
    float S = 0.0f;
#pragma unroll
    for (int w = 0; w < 16; ++w) S += bs[w];
    __hip_atomic_fetch_add(pap, S, __ATOMIC_RELAXED, __HIP_MEMORY_SCOPE_AGENT);
    tick = __hip_atomic_fetch_add(counter, 1, __ATOMIC_ACQ_REL, __HIP_MEMORY_SCOPE_AGENT);
  }
  __syncthreads();
  if (tick != (int)gridDim.x - 1) return;

  // ---- last block: full CG state update (1024 threads) ----
  float rtv = *rt;
  bool act = rtv > TOLF;
  if (!act) {
    if (threadIdx.x == 0) *rt_next = rtv;
    return;
  }
  float papv = __hip_atomic_load(pap, __ATOMIC_RELAXED, __HIP_MEMORY_SCOPE_AGENT);
  float alpha = rtv / papv;
  float val = 0.0f;
#pragma unroll
  for (int j = threadIdx.x * 4; j < N; j += 4096) {
    floatx4 pv = *(const floatx4*)(p + j);
    floatx4 av = *(const floatx4*)(Ap + j);
    floatx4 xv = *(const floatx4*)(x + j);
    floatx4 rv = *(const floatx4*)(r + j);
    xv += alpha * pv;
    rv -= alpha * av;
    *(floatx4*)(x + j) = xv;
    *(floatx4*)(r + j) = rv;
    val += rv.x * rv.x + rv.y * rv.y + rv.z * rv.z + rv.w * rv.w;
  }
  for (int off = 32; off > 0; off >>= 1) val += __shfl_down(val, off, 64);
  __shared__ float rs[17];
  if (lane == 0) rs[wave] = val;
  __syncthreads();
  if (threadIdx.x == 0) {
    float S = 0.0f;
#pragma unroll
    for (int w = 0; w < 16; ++w) S += rs[w];
    rs[16] = S;
    *rt_next = S;
  }
  __syncthreads();
  float beta = rs[16] / rtv;
#pragma unroll
  for (int j = threadIdx.x * 4; j < N; j += 4096) {
    floatx4 rv = *(const floatx4*)(r + j);
    floatx4 pv = *(const floatx4*)(p + j);
    pv = rv + beta * pv;
    *(floatx4*)(p + j) = pv;
  }
}

// ---------------- iteration 1: fp32 matvec fused with bf16 cast ----------------
// Reads M (fp32) once: computes Ap = M @ RHS in fp32 AND writes Mb (bf16 RNE).
__global__ __launch_bounds__(1024, 4) void cg_iter0_cast(
    const float* __restrict__ M, unsigned short* __restrict__ Mb,
    const float* __restrict__ RHS, float* __restrict__ p, float* __restrict__ Ap,
    float* __restrict__ x, float* __restrict__ r, const float* __restrict__ rt,
    float* __restrict__ pap, float* __restrict__ rt_next, int* __restrict__ counter) {
  int wave = threadIdx.x >> 6, lane = threadIdx.x & 63;
  int row0 = blockIdx.x * 32 + wave * 2;
  const float* M0 = M + (size_t)row0 * N;
  const float* M1 = M0 + N;
  unsigned short* B0 = Mb + (size_t)row0 * N;
  unsigned short* B1 = B0 + N;
  float acc0 = 0.0f, acc1 = 0.0f;
#pragma unroll 2
  for (int c = lane * 8; c < N; c += 512) {
    floatx4 a0 = *(const floatx4*)(M0 + c);
    floatx4 a1 = *(const floatx4*)(M0 + c + 4);
    floatx4 b0 = *(const floatx4*)(M1 + c);
    floatx4 b1 = *(const floatx4*)(M1 + c + 4);
    floatx4 pa = *(const floatx4*)(RHS + c);
    floatx4 pb = *(const floatx4*)(RHS + c + 4);
    acc0 += a0.x * pa.x + a0.y * pa.y + a0.z * pa.z + a0.w * pa.w
          + a1.x * pb.x + a1.y * pb.y + a1.z * pb.z + a1.w * pb.w;
    acc1 += b0.x * pa.x + b0.y * pa.y + b0.z * pa.z + b0.w * pa.w
          + b1.x * pb.x + b1.y * pb.y + b1.z * pb.z + b1.w * pb.w;
    uintx4 o0 = {pk_bf2(a0.x, a0.y), pk_bf2(a0.z, a0.w),
                 pk_bf2(a1.x, a1.y), pk_bf2(a1.z, a1.w)};
    uintx4 o1 = {pk_bf2(b0.x, b0.y), pk_bf2(b0.z, b0.w),
                 pk_bf2(b1.x, b1.y), pk_bf2(b1.z, b1.w)};
    *(uintx4*)(B0 + c) = o0;
    *(uintx4*)(B1 + c) = o1;
  }
  finish_iteration(p, x, r, Ap, rt, pap, rt_next, counter, acc0, acc1, row0);
}

// ---------------- iterations 2..NITER: bf16 matvec + fused update ----------------
__global__ __launch_bounds__(1024, 4) void cg_iter(
    const unsigned short* __restrict__ Mb, float* __restrict__ p,
    float* __restrict__ Ap, float* __restrict__ x, float* __restrict__ r,
    const float* __restrict__ rt, float* __restrict__ pap,
    float* __restrict__ rt_next, int* __restrict__ counter) {
  int wave = threadIdx.x >> 6, lane = threadIdx.x & 63;
  int row0 = blockIdx.x * 32 + wave * 2;
  const unsigned short* M0 = Mb + (size_t)row0 * N;
  const unsigned short* M1 = M0 + N;
  float acc0 = 0.0f, acc1 = 0.0f;
#pragma unroll 4
  for (int c = lane * 8; c < N; c += 512) {
    uintx4 m0 = *(const uintx4*)(M0 + c);
    uintx4 m1 = *(const uintx4*)(M1 + c);
    floatx4 pa = *(const floatx4*)(p + c);
    floatx4 pb = *(const floatx4*)(p + c + 4);
    acc0 += bflo(m0.x) * pa.x + bfhi(m0.x) * pa.y
          + bflo(m0.y) * pa.z + bfhi(m0.y) * pa.w
          + bflo(m0.z) * pb.x + bfhi(m0.z) * pb.y
          + bflo(m0.w) * pb.z + bfhi(m0.w) * pb.w;
    acc1 += bflo(m1.x) * pa.x + bfhi(m1.x) * pa.y
          + bflo(m1.y) * pa.z + bfhi(m1.y) * pa.w
          + bflo(m1.z) * pb.x + bfhi(m1.z) * pb.y
          + bflo(m1.w) * pb.z + bfhi(m1.w) * pb.w;
  }
  finish_iteration(p, x, r, Ap, rt, pap, rt_next, counter, acc0, acc1, row0);
}

extern "C" void kernel_launch(void* const* d_in, const int* in_sizes, int n_in,
                              void* d_out, int out_size, void* d_ws, size_t ws_size,
                              hipStream_t stream) {
  const float* M   = (const float*)d_in[1];
  const float* RHS = (const float*)d_in[2];
  float* x = (float*)d_out;          // x accumulates directly in d_out

  char* ws = (char*)d_ws;
  unsigned short* Mb = (unsigned short*)ws;              // N*N bf16 = 134 MB
  float* Ap = (float*)(ws + (size_t)N * N * 2);          // N
  float* r  = Ap + N;                                    // N
  float* p  = r + N;                                     // N
  float* sc = p + N;                                     // scalars
  float* RT  = sc;               // [0..NITER]   (21)
  float* PAP = sc + 21;          // 20
  int*   CNT = (int*)(sc + 41);  // 20

  (void)hipMemsetAsync(sc, 0, 61 * sizeof(float), stream);

  init_kernel<<<N / 256, 256, 0, stream>>>(RHS, x, r, p, &RT[0]);
  cg_iter0_cast<<<N / 32, 1024, 0, stream>>>(M, Mb, RHS, p, Ap, x, r,
                                             &RT[0], &PAP[0], &RT[1], &CNT[0]);
  for (int k = 1; k < NITER; ++k) {
    cg_iter<<<N / 32, 1024, 0, stream>>>(Mb, p, Ap, x, r,
                                         &RT[k], &PAP[k], &RT[k + 1], &CNT[k]);
  }
}